// Round 4
// baseline (486.331 us; speedup 1.0000x reference)
//
#include <hip/hip_runtime.h>
#include <hip/hip_bf16.h>

#define NB 4

__device__ __forceinline__ float sigm(float x) {
    return __builtin_amdgcn_rcpf(1.0f + __expf(-x));
}
__device__ __forceinline__ float tanh_(float x) {
    float e = __expf(2.0f * x);
    return 1.0f - 2.0f * __builtin_amdgcn_rcpf(e + 1.0f);
}

// ============ K1: e1 LSTM(8->64) over 96 steps, NB=4 batches/block, fused e2-xg ============
// 256 threads. Phase A: thread t owns gate-row t (whh[64] in VGPRs) for all 4
// batches; h broadcast via uniform-address LDS reads. Phase B: thread
// (w=t>>6 -> batch, u=t&63 -> unit) does activations + fused e2 gate-preact.
// amdgpu_waves_per_eu(2,2): cap occupancy at 2 waves/EU so the register
// allocator uses up to 256 arch VGPRs and does NOT spill whh[] to AGPRs
// (AGPR spill => v_accvgpr_read per FMA operand, doubling VALU issue — the
// R2 bottleneck: VGPR_Count=64, occupancy 39%, dur 320us).
__global__ __launch_bounds__(256) __attribute__((amdgpu_waves_per_eu(2, 2)))
void k1_e1(
    const float* __restrict__ x,
    const float* __restrict__ e1_Wih, const float* __restrict__ e1_Whh, const float* __restrict__ e1_b,
    const float* __restrict__ e2_Wih, const float* __restrict__ e2_b,
    float* __restrict__ pe2)   // [ts][4096][4]
{
    __shared__ float x_s[NB][768];
    __shared__ float pre[NB][256];
    __shared__ float h_s[NB][64];

    const int t = threadIdx.x;
    const int b0 = blockIdx.x * NB;

    // stage x for 4 batches (coalesced)
    #pragma unroll
    for (int nb = 0; nb < NB; ++nb)
        for (int i = t; i < 768; i += 256)
            x_s[nb][i] = x[(size_t)(b0 + nb) * 768 + i];

    // gate-row weights -> VGPRs
    float whh[64];
    {
        const float4* wp = (const float4*)(e1_Whh + (size_t)t * 64);
        #pragma unroll
        for (int q = 0; q < 16; ++q) {
            float4 w4 = wp[q];
            whh[4*q+0] = w4.x; whh[4*q+1] = w4.y; whh[4*q+2] = w4.z; whh[4*q+3] = w4.w;
        }
        #pragma unroll
        for (int k = 0; k < 64; ++k) asm volatile("" : "+v"(whh[k]));
    }
    float wih[8];
    {
        const float4* wp = (const float4*)(e1_Wih + (size_t)t * 8);
        float4 w0 = wp[0], w1 = wp[1];
        wih[0]=w0.x; wih[1]=w0.y; wih[2]=w0.z; wih[3]=w0.w;
        wih[4]=w1.x; wih[5]=w1.y; wih[6]=w1.z; wih[7]=w1.w;
        #pragma unroll
        for (int k = 0; k < 8; ++k) asm volatile("" : "+v"(wih[k]));
    }
    const float bias = e1_b[t];

    // phase-B statics
    const int w = t >> 6, u = t & 63;
    const int g = u >> 4, part = u & 15;
    float e2w0 = e2_Wih[g * 64 + part * 4 + 0];
    float e2w1 = e2_Wih[g * 64 + part * 4 + 1];
    float e2w2 = e2_Wih[g * 64 + part * 4 + 2];
    float e2w3 = e2_Wih[g * 64 + part * 4 + 3];
    const float e2bias = e2_b[g];
    float c_reg = 0.0f;

    __syncthreads();

    for (int ts = 0; ts < 96; ++ts) {
        // ---------- Phase A: preacts for row t, 4 batches ----------
        float accA[NB], accB[NB];
        #pragma unroll
        for (int nb = 0; nb < NB; ++nb) {
            const float4* xp = (const float4*)&x_s[nb][ts * 8];
            float4 x0 = xp[0], x1 = xp[1];
            float a = bias;
            a = fmaf(x0.x, wih[0], a); a = fmaf(x0.y, wih[1], a);
            a = fmaf(x0.z, wih[2], a); a = fmaf(x0.w, wih[3], a);
            accA[nb] = a;
            float bacc = 0.f;
            bacc = fmaf(x1.x, wih[4], bacc); bacc = fmaf(x1.y, wih[5], bacc);
            bacc = fmaf(x1.z, wih[6], bacc); bacc = fmaf(x1.w, wih[7], bacc);
            accB[nb] = bacc;
        }
        if (ts > 0) {
            #pragma unroll
            for (int kc = 0; kc < 8; ++kc) {
                const int k0 = kc * 8;
                #pragma unroll
                for (int nb = 0; nb < NB; ++nb) {
                    float4 h0 = *(const float4*)&h_s[nb][k0];      // uniform broadcast
                    float4 h1 = *(const float4*)&h_s[nb][k0 + 4];
                    accA[nb] = fmaf(h0.x, whh[k0+0], accA[nb]);
                    accA[nb] = fmaf(h0.y, whh[k0+1], accA[nb]);
                    accA[nb] = fmaf(h0.z, whh[k0+2], accA[nb]);
                    accA[nb] = fmaf(h0.w, whh[k0+3], accA[nb]);
                    accB[nb] = fmaf(h1.x, whh[k0+4], accB[nb]);
                    accB[nb] = fmaf(h1.y, whh[k0+5], accB[nb]);
                    accB[nb] = fmaf(h1.z, whh[k0+6], accB[nb]);
                    accB[nb] = fmaf(h1.w, whh[k0+7], accB[nb]);
                }
            }
        }
        #pragma unroll
        for (int nb = 0; nb < NB; ++nb) pre[nb][t] = accA[nb] + accB[nb];
        __syncthreads();

        // ---------- Phase B: activations for (batch w, unit u) + fused e2 ----------
        {
            float pi = pre[w][u], pf = pre[w][64 + u], pg = pre[w][128 + u], po = pre[w][192 + u];
            float si = sigm(pi), sf = sigm(pf), tg = tanh_(pg), so = sigm(po);
            c_reg = fmaf(sf, c_reg, si * tg);
            float h = so * tanh_(c_reg);
            h_s[w][u] = h;
            // e2 gate-preact: wave w handles batch w; lane (g,part) -> 4-elem slice
            float4 hv = *(const float4*)&h_s[w][part * 4];   // wave-sync RAW, lgkmcnt
            float s = fmaf(hv.x, e2w0, fmaf(hv.y, e2w1, fmaf(hv.z, e2w2, hv.w * e2w3)));
            s += __shfl_xor(s, 1); s += __shfl_xor(s, 2);
            s += __shfl_xor(s, 4); s += __shfl_xor(s, 8);
            if (part == 0)
                pe2[((size_t)ts * 4096 + b0 + w) * 4 + g] = s + e2bias;
        }
        __syncthreads();
    }
}

// ============ K2: e2 recurrence (H=1), lane = batch; build dec_in ============
__global__ void k2_e2(const float* __restrict__ pe2, const float* __restrict__ e2_Whh,
                      const float* __restrict__ x, float* __restrict__ dec_in)
{
    const int b = blockIdx.x * 256 + threadIdx.x;
    const float w0 = e2_Whh[0], w1 = e2_Whh[1], w2 = e2_Whh[2], w3 = e2_Whh[3];
    const float4* pp = (const float4*)pe2;
    float h = 0.f, c = 0.f;
    for (int ts = 0; ts < 96; ++ts) {
        float4 g4 = pp[(size_t)ts * 4096 + b];
        float gi = fmaf(h, w0, g4.x);
        float gf = fmaf(h, w1, g4.y);
        float gg = fmaf(h, w2, g4.z);
        float go = fmaf(h, w3, g4.w);
        c = fmaf(sigm(gf), c, sigm(gi) * tanh_(gg));
        h = sigm(go) * tanh_(c);
        dec_in[(size_t)b * 128 + ts] = fmaxf(h, 0.f);
    }
    #pragma unroll 4
    for (int j = 0; j < 32; ++j)
        dec_in[(size_t)b * 128 + 96 + j] = x[(size_t)b * 768 + (64 + j) * 8];
}

// ============ K3: d1 LSTM(1->16) 128 steps, 4 batches/wave + fused d2-xg ============
__global__ __launch_bounds__(256, 2) void k3_d1(
    const float* __restrict__ dec_in,
    const float* __restrict__ d1_Wih, const float* __restrict__ d1_Whh, const float* __restrict__ d1_b,
    const float* __restrict__ d2_Wih, const float* __restrict__ d2_b,
    float* __restrict__ pd2)   // [ts][4096][4]
{
    __shared__ float din_s[16 * 128];
    __shared__ float h_lds[16][16];

    const int t = threadIdx.x;
    const int w = t >> 6, lane = t & 63;
    const int q = lane >> 4, u = lane & 15;
    const int row = w * 4 + q;
    const size_t b = (size_t)blockIdx.x * 16 + row;

    for (int i = t; i < 2048; i += 256) din_s[i] = dec_in[(size_t)blockIdx.x * 2048 + i];

    float wih_g[4], bg[4], whh_g[4][16], d2w[16];
    #pragma unroll
    for (int g = 0; g < 4; ++g) {
        wih_g[g] = d1_Wih[g * 16 + u];
        bg[g]    = d1_b[g * 16 + u];
        const float4* wp = (const float4*)(d1_Whh + (size_t)(g * 16 + u) * 16);
        #pragma unroll
        for (int qq = 0; qq < 4; ++qq) {
            float4 v = wp[qq];
            whh_g[g][4*qq+0] = v.x; whh_g[g][4*qq+1] = v.y;
            whh_g[g][4*qq+2] = v.z; whh_g[g][4*qq+3] = v.w;
        }
    }
    {
        const float4* wp = (const float4*)(d2_Wih + (size_t)(u & 3) * 16);
        #pragma unroll
        for (int qq = 0; qq < 4; ++qq) {
            float4 v = wp[qq];
            d2w[4*qq+0] = v.x; d2w[4*qq+1] = v.y; d2w[4*qq+2] = v.z; d2w[4*qq+3] = v.w;
        }
    }
    const float d2bias = d2_b[u & 3];

    float h = 0.f, c = 0.f;
    __syncthreads();

    float hv[16];
    for (int ts = 0; ts < 128; ++ts) {
        float xv = din_s[row * 128 + ts];
        float p0 = fmaf(xv, wih_g[0], bg[0]);
        float p1 = fmaf(xv, wih_g[1], bg[1]);
        float p2 = fmaf(xv, wih_g[2], bg[2]);
        float p3 = fmaf(xv, wih_g[3], bg[3]);
        if (ts > 0) {
            const float4* hp = (const float4*)&h_lds[row][0];
            #pragma unroll
            for (int qq = 0; qq < 4; ++qq) {
                float4 v = hp[qq];
                hv[4*qq+0] = v.x; hv[4*qq+1] = v.y; hv[4*qq+2] = v.z; hv[4*qq+3] = v.w;
            }
            #pragma unroll
            for (int k = 0; k < 16; ++k) {
                p0 = fmaf(hv[k], whh_g[0][k], p0);
                p1 = fmaf(hv[k], whh_g[1][k], p1);
                p2 = fmaf(hv[k], whh_g[2][k], p2);
                p3 = fmaf(hv[k], whh_g[3][k], p3);
            }
            if (u < 4) {
                float a = d2bias;
                #pragma unroll
                for (int k = 0; k < 16; ++k) a = fmaf(hv[k], d2w[k], a);
                pd2[((size_t)(ts - 1) * 4096 + b) * 4 + u] = a;
            }
        }
        c = fmaf(sigm(p1), c, sigm(p0) * tanh_(p2));
        h = sigm(p3) * tanh_(c);
        h_lds[row][u] = h;
    }
    {
        const float4* hp = (const float4*)&h_lds[row][0];
        #pragma unroll
        for (int qq = 0; qq < 4; ++qq) {
            float4 v = hp[qq];
            hv[4*qq+0] = v.x; hv[4*qq+1] = v.y; hv[4*qq+2] = v.z; hv[4*qq+3] = v.w;
        }
        if (u < 4) {
            float a = d2bias;
            #pragma unroll
            for (int k = 0; k < 16; ++k) a = fmaf(hv[k], d2w[k], a);
            pd2[((size_t)127 * 4096 + b) * 4 + u] = a;
        }
    }
}

// ============ K5: d2 recurrence (H=1), lane = batch ============
__global__ void k5_d2(const float* __restrict__ pd2, const float* __restrict__ d2_Whh,
                      float* __restrict__ d2h)   // [ts][4096]
{
    const int b = blockIdx.x * 256 + threadIdx.x;
    const float w0 = d2_Whh[0], w1 = d2_Whh[1], w2 = d2_Whh[2], w3 = d2_Whh[3];
    const float4* pp = (const float4*)pd2;
    float h = 0.f, c = 0.f;
    for (int ts = 0; ts < 128; ++ts) {
        float4 g4 = pp[(size_t)ts * 4096 + b];
        float gi = fmaf(h, w0, g4.x);
        float gf = fmaf(h, w1, g4.y);
        float gg = fmaf(h, w2, g4.z);
        float go = fmaf(h, w3, g4.w);
        c = fmaf(sigm(gf), c, sigm(gi) * tanh_(gg));
        h = sigm(go) * tanh_(c);
        d2h[(size_t)ts * 4096 + b] = h;
    }
}

// ============ K6: fc1(128->32) + fc2(32->32), 8 batches/block ============
__global__ __launch_bounds__(256) void k6_fc(
    const float* __restrict__ d2h,
    const float* __restrict__ fc1_W, const float* __restrict__ fc1_b,
    const float* __restrict__ fc2_W, const float* __restrict__ fc2_b,
    float* __restrict__ out)
{
    __shared__ float flat_s[8][128];
    __shared__ float mid_s[8][32];
    const int t = threadIdx.x;
    const int s = t >> 5, o = t & 31;
    const size_t b0 = (size_t)blockIdx.x * 8;

    for (int i = t; i < 1024; i += 256) {
        int ts = i >> 3, ss = i & 7;
        flat_s[ss][ts] = d2h[(size_t)ts * 4096 + b0 + ss];
    }
    __syncthreads();

    float a = fc1_b[o];
    {
        const float4* wp = (const float4*)(fc1_W + (size_t)o * 128);
        const float4* fp = (const float4*)flat_s[s];
        #pragma unroll
        for (int qq = 0; qq < 32; ++qq) {
            float4 f = fp[qq], wv = wp[qq];
            a = fmaf(f.x, wv.x, a); a = fmaf(f.y, wv.y, a);
            a = fmaf(f.z, wv.z, a); a = fmaf(f.w, wv.w, a);
        }
    }
    mid_s[s][o] = a;
    __syncthreads();

    float a2 = fc2_b[o];
    {
        const float4* wp = (const float4*)(fc2_W + (size_t)o * 32);
        const float4* mp = (const float4*)mid_s[s];
        #pragma unroll
        for (int qq = 0; qq < 8; ++qq) {
            float4 m = mp[qq], wv = wp[qq];
            a2 = fmaf(m.x, wv.x, a2); a2 = fmaf(m.y, wv.y, a2);
            a2 = fmaf(m.z, wv.z, a2); a2 = fmaf(m.w, wv.w, a2);
        }
    }
    out[(b0 + s) * 32 + o] = a2;
}

extern "C" void kernel_launch(void* const* d_in, const int* in_sizes, int n_in,
                              void* d_out, int out_size, void* d_ws, size_t ws_size,
                              hipStream_t stream) {
    const float* x      = (const float*)d_in[0];
    const float* e1_Wih = (const float*)d_in[1];
    const float* e1_Whh = (const float*)d_in[2];
    const float* e1_b   = (const float*)d_in[3];
    const float* e2_Wih = (const float*)d_in[4];
    const float* e2_Whh = (const float*)d_in[5];
    const float* e2_b   = (const float*)d_in[6];
    const float* d1_Wih = (const float*)d_in[7];
    const float* d1_Whh = (const float*)d_in[8];
    const float* d1_b   = (const float*)d_in[9];
    const float* d2_Wih = (const float*)d_in[10];
    const float* d2_Whh = (const float*)d_in[11];
    const float* d2_b   = (const float*)d_in[12];
    const float* fc1_W  = (const float*)d_in[13];
    const float* fc1_b  = (const float*)d_in[14];
    const float* fc2_W  = (const float*)d_in[15];
    const float* fc2_b  = (const float*)d_in[16];
    float* out = (float*)d_out;

    float* ws     = (float*)d_ws;
    float* pe2    = ws;                 // [96][4096][4]; reused as pd2 [128][4096][4]
    float* dec_in = ws + 2097152;       // [4096][128]
    float* d2h    = ws + 2621440;       // [128][4096]

    hipLaunchKernelGGL(k1_e1, dim3(1024), dim3(256), 0, stream,
                       x, e1_Wih, e1_Whh, e1_b, e2_Wih, e2_b, pe2);
    hipLaunchKernelGGL(k2_e2, dim3(16), dim3(256), 0, stream, pe2, e2_Whh, x, dec_in);
    hipLaunchKernelGGL(k3_d1, dim3(256), dim3(256), 0, stream,
                       dec_in, d1_Wih, d1_Whh, d1_b, d2_Wih, d2_b, pe2 /*pd2*/);
    hipLaunchKernelGGL(k5_d2, dim3(16), dim3(256), 0, stream, pe2 /*pd2*/, d2_Whh, d2h);
    hipLaunchKernelGGL(k6_fc, dim3(512), dim3(256), 0, stream,
                       d2h, fc1_W, fc1_b, fc2_W, fc2_b, out);
}

// Round 5
// 395.026 us; speedup vs baseline: 1.2311x; 1.2311x over previous
//
#include <hip/hip_runtime.h>
#include <hip/hip_bf16.h>

#define NB8 8

__device__ __forceinline__ float sigm(float x) {
    return __builtin_amdgcn_rcpf(1.0f + __expf(-x));
}
__device__ __forceinline__ float tanh_(float x) {
    float e = __expf(2.0f * x);
    return 1.0f - 2.0f * __builtin_amdgcn_rcpf(e + 1.0f);
}

// ============ K1: e1 LSTM(8->64), 96 steps, NB8=8 batches/block ============
// 512 threads. Phase A: thread (half=t>>8, r=t&255) owns HALF of gate-row r
// (whh[32] in VGPRs — ~55 VGPR total demand, fits under any allocator budget,
// so no AGPR spill by construction; R2/R3 showed 64-152 reg demand always
// spills to AGPR => v_accvgpr_read per FMA). Partial preacts -> LDS pp[].
// Phase B: thread (nb=t>>6, u=t&63) sums halves, activations, fused e2-xg.
__global__ __launch_bounds__(512) __attribute__((amdgpu_waves_per_eu(4, 4)))
void k1_e1(
    const float* __restrict__ x,
    const float* __restrict__ e1_Wih, const float* __restrict__ e1_Whh, const float* __restrict__ e1_b,
    const float* __restrict__ e2_Wih, const float* __restrict__ e2_b,
    float* __restrict__ pe2)   // [ts][4096][4]
{
    __shared__ float x_s[NB8][768];        // 24.5 KB
    __shared__ float pp[2][NB8][256];      // 16 KB partial preacts
    __shared__ float h_s[NB8][64];         // 2 KB

    const int t = threadIdx.x;             // 0..511
    const int half = t >> 8;               // 0/1: K-half of the dot product
    const int r = t & 255;                 // gate-row
    const int b0 = blockIdx.x * NB8;

    // stage x for 8 batches (coalesced flat copy)
    for (int i = t; i < NB8 * 768; i += 512)
        ((float*)x_s)[i] = x[(size_t)b0 * 768 + i];

    // half-row weights -> VGPRs (32 + 4: comfortably register-resident)
    float whh[32];
    {
        const float4* wp = (const float4*)(e1_Whh + (size_t)r * 64 + half * 32);
        #pragma unroll
        for (int q = 0; q < 8; ++q) {
            float4 w4 = wp[q];
            whh[4*q+0] = w4.x; whh[4*q+1] = w4.y; whh[4*q+2] = w4.z; whh[4*q+3] = w4.w;
        }
    }
    float wih4[4];
    {
        const float4* wp = (const float4*)(e1_Wih + (size_t)r * 8 + half * 4);
        float4 w4 = wp[0];
        wih4[0] = w4.x; wih4[1] = w4.y; wih4[2] = w4.z; wih4[3] = w4.w;
    }
    const float bias = (half == 0) ? e1_b[r] : 0.0f;

    // phase-B statics: thread -> (batch nb, unit u)
    const int nb = t >> 6, u = t & 63;
    const int g2 = u >> 4, part = u & 15;
    const float e2w0 = e2_Wih[g2 * 64 + part * 4 + 0];
    const float e2w1 = e2_Wih[g2 * 64 + part * 4 + 1];
    const float e2w2 = e2_Wih[g2 * 64 + part * 4 + 2];
    const float e2w3 = e2_Wih[g2 * 64 + part * 4 + 3];
    const float e2bias = e2_b[g2];
    float c_reg = 0.0f;

    __syncthreads();

    for (int ts = 0; ts < 96; ++ts) {
        // ---------- Phase A: partial preacts (half K) for row r, 8 batches ----------
        float acc[NB8];
        #pragma unroll
        for (int n = 0; n < NB8; ++n) {
            const float4 xv = *(const float4*)&x_s[n][ts * 8 + half * 4];
            float a = bias;
            a = fmaf(xv.x, wih4[0], a); a = fmaf(xv.y, wih4[1], a);
            a = fmaf(xv.z, wih4[2], a); a = fmaf(xv.w, wih4[3], a);
            acc[n] = a;
        }
        if (ts > 0) {
            #pragma unroll
            for (int kc = 0; kc < 8; ++kc) {
                const int k0 = kc * 4;
                #pragma unroll
                for (int n = 0; n < NB8; ++n) {
                    const float4 hv = *(const float4*)&h_s[n][half * 32 + k0]; // uniform bcast
                    acc[n] = fmaf(hv.x, whh[k0+0], acc[n]);
                    acc[n] = fmaf(hv.y, whh[k0+1], acc[n]);
                    acc[n] = fmaf(hv.z, whh[k0+2], acc[n]);
                    acc[n] = fmaf(hv.w, whh[k0+3], acc[n]);
                }
            }
        }
        #pragma unroll
        for (int n = 0; n < NB8; ++n) pp[half][n][r] = acc[n];
        __syncthreads();

        // ---------- Phase B: combine halves, activations, fused e2-xg ----------
        {
            float pi = pp[0][nb][u]       + pp[1][nb][u];
            float pf = pp[0][nb][64 + u]  + pp[1][nb][64 + u];
            float pg = pp[0][nb][128 + u] + pp[1][nb][128 + u];
            float po = pp[0][nb][192 + u] + pp[1][nb][192 + u];
            float si = sigm(pi), sf = sigm(pf), tg = tanh_(pg), so = sigm(po);
            c_reg = fmaf(sf, c_reg, si * tg);
            float h = so * tanh_(c_reg);
            h_s[nb][u] = h;
            // e2 gate-preact: wave nb handles batch nb; lane (g2,part) -> 4-elem slice
            float4 hv = *(const float4*)&h_s[nb][part * 4];   // same-wave RAW, lgkmcnt
            float s = fmaf(hv.x, e2w0, fmaf(hv.y, e2w1, fmaf(hv.z, e2w2, hv.w * e2w3)));
            s += __shfl_xor(s, 1); s += __shfl_xor(s, 2);
            s += __shfl_xor(s, 4); s += __shfl_xor(s, 8);
            if (part == 0)
                pe2[((size_t)ts * 4096 + b0 + nb) * 4 + g2] = s + e2bias;
        }
        __syncthreads();
    }
}

// ============ K2: e2 recurrence (H=1), lane = batch; build dec_in ============
__global__ void k2_e2(const float* __restrict__ pe2, const float* __restrict__ e2_Whh,
                      const float* __restrict__ x, float* __restrict__ dec_in)
{
    const int b = blockIdx.x * 256 + threadIdx.x;
    const float w0 = e2_Whh[0], w1 = e2_Whh[1], w2 = e2_Whh[2], w3 = e2_Whh[3];
    const float4* pp = (const float4*)pe2;
    float h = 0.f, c = 0.f;
    for (int ts = 0; ts < 96; ++ts) {
        float4 g4 = pp[(size_t)ts * 4096 + b];
        float gi = fmaf(h, w0, g4.x);
        float gf = fmaf(h, w1, g4.y);
        float gg = fmaf(h, w2, g4.z);
        float go = fmaf(h, w3, g4.w);
        c = fmaf(sigm(gf), c, sigm(gi) * tanh_(gg));
        h = sigm(go) * tanh_(c);
        dec_in[(size_t)b * 128 + ts] = fmaxf(h, 0.f);
    }
    #pragma unroll 4
    for (int j = 0; j < 32; ++j)
        dec_in[(size_t)b * 128 + 96 + j] = x[(size_t)b * 768 + (64 + j) * 8];
}

// ============ K3: d1 LSTM(1->16) 128 steps, 4 batches/wave + fused d2-xg ============
__global__ __launch_bounds__(256, 2) void k3_d1(
    const float* __restrict__ dec_in,
    const float* __restrict__ d1_Wih, const float* __restrict__ d1_Whh, const float* __restrict__ d1_b,
    const float* __restrict__ d2_Wih, const float* __restrict__ d2_b,
    float* __restrict__ pd2)   // [ts][4096][4]
{
    __shared__ float din_s[16 * 128];
    __shared__ float h_lds[16][16];

    const int t = threadIdx.x;
    const int w = t >> 6, lane = t & 63;
    const int q = lane >> 4, u = lane & 15;
    const int row = w * 4 + q;
    const size_t b = (size_t)blockIdx.x * 16 + row;

    for (int i = t; i < 2048; i += 256) din_s[i] = dec_in[(size_t)blockIdx.x * 2048 + i];

    float wih_g[4], bg[4], whh_g[4][16], d2w[16];
    #pragma unroll
    for (int g = 0; g < 4; ++g) {
        wih_g[g] = d1_Wih[g * 16 + u];
        bg[g]    = d1_b[g * 16 + u];
        const float4* wp = (const float4*)(d1_Whh + (size_t)(g * 16 + u) * 16);
        #pragma unroll
        for (int qq = 0; qq < 4; ++qq) {
            float4 v = wp[qq];
            whh_g[g][4*qq+0] = v.x; whh_g[g][4*qq+1] = v.y;
            whh_g[g][4*qq+2] = v.z; whh_g[g][4*qq+3] = v.w;
        }
    }
    {
        const float4* wp = (const float4*)(d2_Wih + (size_t)(u & 3) * 16);
        #pragma unroll
        for (int qq = 0; qq < 4; ++qq) {
            float4 v = wp[qq];
            d2w[4*qq+0] = v.x; d2w[4*qq+1] = v.y; d2w[4*qq+2] = v.z; d2w[4*qq+3] = v.w;
        }
    }
    const float d2bias = d2_b[u & 3];

    float h = 0.f, c = 0.f;
    __syncthreads();

    float hv[16];
    for (int ts = 0; ts < 128; ++ts) {
        float xv = din_s[row * 128 + ts];
        float p0 = fmaf(xv, wih_g[0], bg[0]);
        float p1 = fmaf(xv, wih_g[1], bg[1]);
        float p2 = fmaf(xv, wih_g[2], bg[2]);
        float p3 = fmaf(xv, wih_g[3], bg[3]);
        if (ts > 0) {
            const float4* hp = (const float4*)&h_lds[row][0];
            #pragma unroll
            for (int qq = 0; qq < 4; ++qq) {
                float4 v = hp[qq];
                hv[4*qq+0] = v.x; hv[4*qq+1] = v.y; hv[4*qq+2] = v.z; hv[4*qq+3] = v.w;
            }
            #pragma unroll
            for (int k = 0; k < 16; ++k) {
                p0 = fmaf(hv[k], whh_g[0][k], p0);
                p1 = fmaf(hv[k], whh_g[1][k], p1);
                p2 = fmaf(hv[k], whh_g[2][k], p2);
                p3 = fmaf(hv[k], whh_g[3][k], p3);
            }
            if (u < 4) {
                float a = d2bias;
                #pragma unroll
                for (int k = 0; k < 16; ++k) a = fmaf(hv[k], d2w[k], a);
                pd2[((size_t)(ts - 1) * 4096 + b) * 4 + u] = a;
            }
        }
        c = fmaf(sigm(p1), c, sigm(p0) * tanh_(p2));
        h = sigm(p3) * tanh_(c);
        h_lds[row][u] = h;
    }
    {
        const float4* hp = (const float4*)&h_lds[row][0];
        #pragma unroll
        for (int qq = 0; qq < 4; ++qq) {
            float4 v = hp[qq];
            hv[4*qq+0] = v.x; hv[4*qq+1] = v.y; hv[4*qq+2] = v.z; hv[4*qq+3] = v.w;
        }
        if (u < 4) {
            float a = d2bias;
            #pragma unroll
            for (int k = 0; k < 16; ++k) a = fmaf(hv[k], d2w[k], a);
            pd2[((size_t)127 * 4096 + b) * 4 + u] = a;
        }
    }
}

// ============ K5: d2 recurrence (H=1), lane = batch ============
__global__ void k5_d2(const float* __restrict__ pd2, const float* __restrict__ d2_Whh,
                      float* __restrict__ d2h)   // [ts][4096]
{
    const int b = blockIdx.x * 256 + threadIdx.x;
    const float w0 = d2_Whh[0], w1 = d2_Whh[1], w2 = d2_Whh[2], w3 = d2_Whh[3];
    const float4* pp = (const float4*)pd2;
    float h = 0.f, c = 0.f;
    for (int ts = 0; ts < 128; ++ts) {
        float4 g4 = pp[(size_t)ts * 4096 + b];
        float gi = fmaf(h, w0, g4.x);
        float gf = fmaf(h, w1, g4.y);
        float gg = fmaf(h, w2, g4.z);
        float go = fmaf(h, w3, g4.w);
        c = fmaf(sigm(gf), c, sigm(gi) * tanh_(gg));
        h = sigm(go) * tanh_(c);
        d2h[(size_t)ts * 4096 + b] = h;
    }
}

// ============ K6: fc1(128->32) + fc2(32->32), 8 batches/block ============
__global__ __launch_bounds__(256) void k6_fc(
    const float* __restrict__ d2h,
    const float* __restrict__ fc1_W, const float* __restrict__ fc1_b,
    const float* __restrict__ fc2_W, const float* __restrict__ fc2_b,
    float* __restrict__ out)
{
    __shared__ float flat_s[8][128];
    __shared__ float mid_s[8][32];
    const int t = threadIdx.x;
    const int s = t >> 5, o = t & 31;
    const size_t b0 = (size_t)blockIdx.x * 8;

    for (int i = t; i < 1024; i += 256) {
        int ts = i >> 3, ss = i & 7;
        flat_s[ss][ts] = d2h[(size_t)ts * 4096 + b0 + ss];
    }
    __syncthreads();

    float a = fc1_b[o];
    {
        const float4* wp = (const float4*)(fc1_W + (size_t)o * 128);
        const float4* fp = (const float4*)flat_s[s];
        #pragma unroll
        for (int qq = 0; qq < 32; ++qq) {
            float4 f = fp[qq], wv = wp[qq];
            a = fmaf(f.x, wv.x, a); a = fmaf(f.y, wv.y, a);
            a = fmaf(f.z, wv.z, a); a = fmaf(f.w, wv.w, a);
        }
    }
    mid_s[s][o] = a;
    __syncthreads();

    float a2 = fc2_b[o];
    {
        const float4* wp = (const float4*)(fc2_W + (size_t)o * 32);
        const float4* mp = (const float4*)mid_s[s];
        #pragma unroll
        for (int qq = 0; qq < 8; ++qq) {
            float4 m = mp[qq], wv = wp[qq];
            a2 = fmaf(m.x, wv.x, a2); a2 = fmaf(m.y, wv.y, a2);
            a2 = fmaf(m.z, wv.z, a2); a2 = fmaf(m.w, wv.w, a2);
        }
    }
    out[(b0 + s) * 32 + o] = a2;
}

extern "C" void kernel_launch(void* const* d_in, const int* in_sizes, int n_in,
                              void* d_out, int out_size, void* d_ws, size_t ws_size,
                              hipStream_t stream) {
    const float* x      = (const float*)d_in[0];
    const float* e1_Wih = (const float*)d_in[1];
    const float* e1_Whh = (const float*)d_in[2];
    const float* e1_b   = (const float*)d_in[3];
    const float* e2_Wih = (const float*)d_in[4];
    const float* e2_Whh = (const float*)d_in[5];
    const float* e2_b   = (const float*)d_in[6];
    const float* d1_Wih = (const float*)d_in[7];
    const float* d1_Whh = (const float*)d_in[8];
    const float* d1_b   = (const float*)d_in[9];
    const float* d2_Wih = (const float*)d_in[10];
    const float* d2_Whh = (const float*)d_in[11];
    const float* d2_b   = (const float*)d_in[12];
    const float* fc1_W  = (const float*)d_in[13];
    const float* fc1_b  = (const float*)d_in[14];
    const float* fc2_W  = (const float*)d_in[15];
    const float* fc2_b  = (const float*)d_in[16];
    float* out = (float*)d_out;

    float* ws     = (float*)d_ws;
    float* pe2    = ws;                 // [96][4096][4]; reused as pd2 [128][4096][4]
    float* dec_in = ws + 2097152;       // [4096][128]
    float* d2h    = ws + 2621440;       // [128][4096]

    hipLaunchKernelGGL(k1_e1, dim3(512), dim3(512), 0, stream,
                       x, e1_Wih, e1_Whh, e1_b, e2_Wih, e2_b, pe2);
    hipLaunchKernelGGL(k2_e2, dim3(16), dim3(256), 0, stream, pe2, e2_Whh, x, dec_in);
    hipLaunchKernelGGL(k3_d1, dim3(256), dim3(256), 0, stream,
                       dec_in, d1_Wih, d1_Whh, d1_b, d2_Wih, d2_b, pe2 /*pd2*/);
    hipLaunchKernelGGL(k5_d2, dim3(16), dim3(256), 0, stream, pe2 /*pd2*/, d2_Whh, d2h);
    hipLaunchKernelGGL(k6_fc, dim3(512), dim3(256), 0, stream,
                       d2h, fc1_W, fc1_b, fc2_W, fc2_b, out);
}

// Round 6
// 214.409 us; speedup vs baseline: 2.2682x; 1.8424x over previous
//
#include <hip/hip_runtime.h>
#include <hip/hip_bf16.h>

typedef __attribute__((ext_vector_type(8))) short bf16x8;
typedef __attribute__((ext_vector_type(4))) float f32x4;

__device__ __forceinline__ float sigm(float x) {
    return __builtin_amdgcn_rcpf(1.0f + __expf(-x));
}
__device__ __forceinline__ float tanh_(float x) {
    float e = __expf(2.0f * x);
    return 1.0f - 2.0f * __builtin_amdgcn_rcpf(e + 1.0f);
}
__device__ __forceinline__ ushort f2bf(float f) {   // RNE float->bf16
    uint u = __float_as_uint(f);
    u = u + 0x7FFFu + ((u >> 16) & 1u);
    return (ushort)(u >> 16);
}
__device__ __forceinline__ float bf2f(ushort s) { return __uint_as_float(((uint)s) << 16); }

// ============ K1: e1 LSTM(8->64) via MFMA (bf16 hi/lo emulation of fp32) ============
// 16 batches/block, 512 threads (8 waves), grid 256 = 1 block/CU.
// Per step: preacts = one 16x272x64 matmul on the matrix pipe:
//   rows 0..255 = e1 gates (i,f,g,o x 64), rows 256..259 = e2 xg (fused).
// Accuracy: h,W split hi+lo bf16; pre = hi*Whi + lo*Whi + hi*Wlo (+ x-part and
// bias via a 3rd K-chunk with A2=[xhi,xlo,xhi,1,1,0..]) -> rel err ~2^-17.
// Wave wv owns tiles {2wv, 2wv+1}; wave 0 additionally owns the e2 tile (16).
// Phase B: thread (wv -> 2 batches, lane -> unit) does gate nonlinearities,
// writes h back as bf16 hi/lo, builds next step's A2, wave 7 stores pe2.
__global__ __launch_bounds__(512) __attribute__((amdgpu_waves_per_eu(2, 2)))
void k1_e1(
    const float* __restrict__ x,
    const float* __restrict__ e1_Wih, const float* __restrict__ e1_Whh, const float* __restrict__ e1_b,
    const float* __restrict__ e2_Wih, const float* __restrict__ e2_b,
    float* __restrict__ pe2)   // [ts][4096][4]
{
    __shared__ float x_s[16 * 768];               // 48 KB
    __shared__ float pre_s[272 * 17];             // 18 KB, stride 17 -> conflict-free
    __shared__ __align__(16) ushort h_hi_s[16 * 72];   // rows padded to 72 bf16 (2-way = free)
    __shared__ __align__(16) ushort h_lo_s[16 * 72];
    __shared__ __align__(16) ushort x2_s[16 * 40];     // A2 chunk, padded rows

    const int t = threadIdx.x;
    const int b0 = blockIdx.x * 16;
    const int l = t & 63, wv = t >> 6;
    const int nLoc = l & 15, sub = l >> 4;

    // ---- stage x ----
    for (int i = t; i < 16 * 768; i += 512) x_s[i] = x[(size_t)b0 * 768 + i];
    __syncthreads();

    // ---- zero h, build A2 for ts=0 (incl. constant columns 24..31) ----
    for (int i = t; i < 16 * 72; i += 512) { h_hi_s[i] = 0; h_lo_s[i] = 0; }
    {
        int bb = t >> 5, pos = t & 31;
        ushort v = 0;
        if (pos < 24) {
            float xv = x_s[bb * 768 + (pos & 7)];
            ushort hi = f2bf(xv);
            v = (pos < 8) ? hi : (pos < 16) ? f2bf(xv - bf2f(hi)) : hi;
        } else if (pos == 24 || pos == 25) v = 0x3F80;   // 1.0bf
        x2_s[bb * 40 + pos] = v;
    }

    // ---- weight fragments -> registers (hi/lo bf16) ----
    auto loadW = [&](const float* rowbase, int k0, bool valid, bf16x8& hi8, bf16x8& lo8) {
        float f[8];
        if (valid) {
            float4 v0 = ((const float4*)(rowbase + k0))[0];
            float4 v1 = ((const float4*)(rowbase + k0))[1];
            f[0]=v0.x; f[1]=v0.y; f[2]=v0.z; f[3]=v0.w;
            f[4]=v1.x; f[5]=v1.y; f[6]=v1.z; f[7]=v1.w;
        } else {
            #pragma unroll
            for (int j = 0; j < 8; ++j) f[j] = 0.f;
        }
        #pragma unroll
        for (int j = 0; j < 8; ++j) {
            ushort h = f2bf(f[j]);
            hi8[j] = (short)h;
            lo8[j] = (short)f2bf(f[j] - bf2f(h));
        }
    };

    bf16x8 Bh0c0, Bl0c0, Bh0c1, Bl0c1, Bh1c0, Bl1c0, Bh1c1, Bl1c1;
    bf16x8 Bh2c0, Bl2c0, Bh2c1, Bl2c1, B2_0, B2_1, B2_2;
    {
        const int T0 = 2 * wv, T1 = 2 * wv + 1;
        const float* r0 = e1_Whh + (size_t)(T0 * 16 + nLoc) * 64;
        const float* r1 = e1_Whh + (size_t)(T1 * 16 + nLoc) * 64;
        loadW(r0, sub * 8,      true, Bh0c0, Bl0c0);
        loadW(r0, 32 + sub * 8, true, Bh0c1, Bl0c1);
        loadW(r1, sub * 8,      true, Bh1c0, Bl1c0);
        loadW(r1, 32 + sub * 8, true, Bh1c1, Bl1c1);
        const bool v2 = (wv == 0) && (nLoc < 4);
        const float* r2 = v2 ? (e2_Wih + (size_t)nLoc * 64) : r0;
        loadW(r2, sub * 8,      v2, Bh2c0, Bl2c0);
        loadW(r2, 32 + sub * 8, v2, Bh2c1, Bl2c1);

        auto loadB2e1 = [&](int T, bf16x8& o) {
            const int n = T * 16 + nLoc;
            if (sub < 3) {   // rows 0-7: Wih_hi, 8-15: Wih_hi (xlo), 16-23: Wih_lo
                float4 w0 = ((const float4*)(e1_Wih + n * 8))[0];
                float4 w1 = ((const float4*)(e1_Wih + n * 8))[1];
                float f[8] = {w0.x, w0.y, w0.z, w0.w, w1.x, w1.y, w1.z, w1.w};
                #pragma unroll
                for (int j = 0; j < 8; ++j) {
                    ushort h = f2bf(f[j]);
                    o[j] = (sub < 2) ? (short)h : (short)f2bf(f[j] - bf2f(h));
                }
            } else {         // rows 24,25: bias hi/lo (paired with A2 = 1.0)
                float bb = e1_b[n];
                ushort h = f2bf(bb);
                o[0] = (short)h; o[1] = (short)f2bf(bb - bf2f(h));
                #pragma unroll
                for (int j = 2; j < 8; ++j) o[j] = 0;
            }
        };
        loadB2e1(T0, B2_0);
        loadB2e1(T1, B2_1);
        #pragma unroll
        for (int j = 0; j < 8; ++j) B2_2[j] = 0;
        if (wv == 0 && sub == 3 && nLoc < 4) {
            float bb = e2_b[nLoc];
            ushort h = f2bf(bb);
            B2_2[0] = (short)h; B2_2[1] = (short)f2bf(bb - bf2f(h));
        }
    }
    const int pb0 = wv * 2, pb1 = wv * 2 + 1;
    float c0r = 0.f, c1r = 0.f;
    __syncthreads();

    for (int ts = 0; ts < 96; ++ts) {
        // ---------- Phase A: MFMA preacts ----------
        bf16x8 Ah0 = *(const bf16x8*)&h_hi_s[nLoc * 72 + sub * 8];
        bf16x8 Ah1 = *(const bf16x8*)&h_hi_s[nLoc * 72 + 32 + sub * 8];
        bf16x8 Al0 = *(const bf16x8*)&h_lo_s[nLoc * 72 + sub * 8];
        bf16x8 Al1 = *(const bf16x8*)&h_lo_s[nLoc * 72 + 32 + sub * 8];
        bf16x8 A2v = *(const bf16x8*)&x2_s[nLoc * 40 + sub * 8];

        f32x4 acc0 = {0.f, 0.f, 0.f, 0.f}, acc1 = {0.f, 0.f, 0.f, 0.f};
        acc0 = __builtin_amdgcn_mfma_f32_16x16x32_bf16(Ah0, Bh0c0, acc0, 0, 0, 0);
        acc0 = __builtin_amdgcn_mfma_f32_16x16x32_bf16(Ah1, Bh0c1, acc0, 0, 0, 0);
        acc0 = __builtin_amdgcn_mfma_f32_16x16x32_bf16(Al0, Bh0c0, acc0, 0, 0, 0);
        acc0 = __builtin_amdgcn_mfma_f32_16x16x32_bf16(Al1, Bh0c1, acc0, 0, 0, 0);
        acc0 = __builtin_amdgcn_mfma_f32_16x16x32_bf16(Ah0, Bl0c0, acc0, 0, 0, 0);
        acc0 = __builtin_amdgcn_mfma_f32_16x16x32_bf16(Ah1, Bl0c1, acc0, 0, 0, 0);
        acc0 = __builtin_amdgcn_mfma_f32_16x16x32_bf16(A2v, B2_0,  acc0, 0, 0, 0);

        acc1 = __builtin_amdgcn_mfma_f32_16x16x32_bf16(Ah0, Bh1c0, acc1, 0, 0, 0);
        acc1 = __builtin_amdgcn_mfma_f32_16x16x32_bf16(Ah1, Bh1c1, acc1, 0, 0, 0);
        acc1 = __builtin_amdgcn_mfma_f32_16x16x32_bf16(Al0, Bh1c0, acc1, 0, 0, 0);
        acc1 = __builtin_amdgcn_mfma_f32_16x16x32_bf16(Al1, Bh1c1, acc1, 0, 0, 0);
        acc1 = __builtin_amdgcn_mfma_f32_16x16x32_bf16(Ah0, Bl1c0, acc1, 0, 0, 0);
        acc1 = __builtin_amdgcn_mfma_f32_16x16x32_bf16(Ah1, Bl1c1, acc1, 0, 0, 0);
        acc1 = __builtin_amdgcn_mfma_f32_16x16x32_bf16(A2v, B2_1,  acc1, 0, 0, 0);

        {   // C layout: col(lane&15)=gate-in-tile, row((lane>>4)*4+i)=batch
            int r0 = (2 * wv * 16 + nLoc) * 17 + sub * 4;
            pre_s[r0 + 0] = acc0[0]; pre_s[r0 + 1] = acc0[1];
            pre_s[r0 + 2] = acc0[2]; pre_s[r0 + 3] = acc0[3];
            int r1 = ((2 * wv + 1) * 16 + nLoc) * 17 + sub * 4;
            pre_s[r1 + 0] = acc1[0]; pre_s[r1 + 1] = acc1[1];
            pre_s[r1 + 2] = acc1[2]; pre_s[r1 + 3] = acc1[3];
        }
        if (wv == 0) {   // e2 tile (rows 256..271)
            f32x4 acc2 = {0.f, 0.f, 0.f, 0.f};
            acc2 = __builtin_amdgcn_mfma_f32_16x16x32_bf16(Ah0, Bh2c0, acc2, 0, 0, 0);
            acc2 = __builtin_amdgcn_mfma_f32_16x16x32_bf16(Ah1, Bh2c1, acc2, 0, 0, 0);
            acc2 = __builtin_amdgcn_mfma_f32_16x16x32_bf16(Al0, Bh2c0, acc2, 0, 0, 0);
            acc2 = __builtin_amdgcn_mfma_f32_16x16x32_bf16(Al1, Bh2c1, acc2, 0, 0, 0);
            acc2 = __builtin_amdgcn_mfma_f32_16x16x32_bf16(Ah0, Bl2c0, acc2, 0, 0, 0);
            acc2 = __builtin_amdgcn_mfma_f32_16x16x32_bf16(Ah1, Bl2c1, acc2, 0, 0, 0);
            acc2 = __builtin_amdgcn_mfma_f32_16x16x32_bf16(A2v, B2_2,  acc2, 0, 0, 0);
            int r2 = (256 + nLoc) * 17 + sub * 4;
            pre_s[r2 + 0] = acc2[0]; pre_s[r2 + 1] = acc2[1];
            pre_s[r2 + 2] = acc2[2]; pre_s[r2 + 3] = acc2[3];
        }
        __syncthreads();

        // ---------- Phase B: activations (2 batches x unit l) ----------
        {
            const int u = l;
            float pi0 = pre_s[(u)*17 + pb0],       pf0 = pre_s[(64 + u)*17 + pb0];
            float pg0 = pre_s[(128 + u)*17 + pb0], po0 = pre_s[(192 + u)*17 + pb0];
            float pi1 = pre_s[(u)*17 + pb1],       pf1 = pre_s[(64 + u)*17 + pb1];
            float pg1 = pre_s[(128 + u)*17 + pb1], po1 = pre_s[(192 + u)*17 + pb1];

            c0r = fmaf(sigm(pf0), c0r, sigm(pi0) * tanh_(pg0));
            float h0 = sigm(po0) * tanh_(c0r);
            c1r = fmaf(sigm(pf1), c1r, sigm(pi1) * tanh_(pg1));
            float h1 = sigm(po1) * tanh_(c1r);

            ushort hh0 = f2bf(h0);
            h_hi_s[pb0 * 72 + u] = hh0;
            h_lo_s[pb0 * 72 + u] = f2bf(h0 - bf2f(hh0));
            ushort hh1 = f2bf(h1);
            h_hi_s[pb1 * 72 + u] = hh1;
            h_lo_s[pb1 * 72 + u] = f2bf(h1 - bf2f(hh1));
        }
        if (wv == 7) {   // store e2 xg (coalesced 256B)
            int bb = l >> 2, g = l & 3;
            pe2[((size_t)ts * 4096 + b0 + bb) * 4 + g] = pre_s[(256 + g) * 17 + bb];
        }
        if (ts < 95) {   // build A2 for ts+1
            int bb = t >> 5, pos = t & 31;
            if (pos < 24) {
                float xv = x_s[bb * 768 + (ts + 1) * 8 + (pos & 7)];
                ushort hi = f2bf(xv);
                ushort v = (pos < 8) ? hi : (pos < 16) ? f2bf(xv - bf2f(hi)) : hi;
                x2_s[bb * 40 + pos] = v;
            }
        }
        __syncthreads();
    }
}

// ============ K2: e2 recurrence (H=1), lane = batch; build dec_in ============
__global__ void k2_e2(const float* __restrict__ pe2, const float* __restrict__ e2_Whh,
                      const float* __restrict__ x, float* __restrict__ dec_in)
{
    const int b = blockIdx.x * 256 + threadIdx.x;
    const float w0 = e2_Whh[0], w1 = e2_Whh[1], w2 = e2_Whh[2], w3 = e2_Whh[3];
    const float4* pp = (const float4*)pe2;
    float h = 0.f, c = 0.f;
    for (int ts = 0; ts < 96; ++ts) {
        float4 g4 = pp[(size_t)ts * 4096 + b];
        float gi = fmaf(h, w0, g4.x);
        float gf = fmaf(h, w1, g4.y);
        float gg = fmaf(h, w2, g4.z);
        float go = fmaf(h, w3, g4.w);
        c = fmaf(sigm(gf), c, sigm(gi) * tanh_(gg));
        h = sigm(go) * tanh_(c);
        dec_in[(size_t)b * 128 + ts] = fmaxf(h, 0.f);
    }
    #pragma unroll 4
    for (int j = 0; j < 32; ++j)
        dec_in[(size_t)b * 128 + 96 + j] = x[(size_t)b * 768 + (64 + j) * 8];
}

// ============ K3: d1 LSTM(1->16) 128 steps, 4 batches/wave + fused d2-xg ============
__global__ __launch_bounds__(256, 2) void k3_d1(
    const float* __restrict__ dec_in,
    const float* __restrict__ d1_Wih, const float* __restrict__ d1_Whh, const float* __restrict__ d1_b,
    const float* __restrict__ d2_Wih, const float* __restrict__ d2_b,
    float* __restrict__ pd2)   // [ts][4096][4]
{
    __shared__ float din_s[16 * 128];
    __shared__ float h_lds[16][16];

    const int t = threadIdx.x;
    const int w = t >> 6, lane = t & 63;
    const int q = lane >> 4, u = lane & 15;
    const int row = w * 4 + q;
    const size_t b = (size_t)blockIdx.x * 16 + row;

    for (int i = t; i < 2048; i += 256) din_s[i] = dec_in[(size_t)blockIdx.x * 2048 + i];

    float wih_g[4], bg[4], whh_g[4][16], d2w[16];
    #pragma unroll
    for (int g = 0; g < 4; ++g) {
        wih_g[g] = d1_Wih[g * 16 + u];
        bg[g]    = d1_b[g * 16 + u];
        const float4* wp = (const float4*)(d1_Whh + (size_t)(g * 16 + u) * 16);
        #pragma unroll
        for (int qq = 0; qq < 4; ++qq) {
            float4 v = wp[qq];
            whh_g[g][4*qq+0] = v.x; whh_g[g][4*qq+1] = v.y;
            whh_g[g][4*qq+2] = v.z; whh_g[g][4*qq+3] = v.w;
        }
    }
    {
        const float4* wp = (const float4*)(d2_Wih + (size_t)(u & 3) * 16);
        #pragma unroll
        for (int qq = 0; qq < 4; ++qq) {
            float4 v = wp[qq];
            d2w[4*qq+0] = v.x; d2w[4*qq+1] = v.y; d2w[4*qq+2] = v.z; d2w[4*qq+3] = v.w;
        }
    }
    const float d2bias = d2_b[u & 3];

    float h = 0.f, c = 0.f;
    __syncthreads();

    float hv[16];
    for (int ts = 0; ts < 128; ++ts) {
        float xv = din_s[row * 128 + ts];
        float p0 = fmaf(xv, wih_g[0], bg[0]);
        float p1 = fmaf(xv, wih_g[1], bg[1]);
        float p2 = fmaf(xv, wih_g[2], bg[2]);
        float p3 = fmaf(xv, wih_g[3], bg[3]);
        if (ts > 0) {
            const float4* hp = (const float4*)&h_lds[row][0];
            #pragma unroll
            for (int qq = 0; qq < 4; ++qq) {
                float4 v = hp[qq];
                hv[4*qq+0] = v.x; hv[4*qq+1] = v.y; hv[4*qq+2] = v.z; hv[4*qq+3] = v.w;
            }
            #pragma unroll
            for (int k = 0; k < 16; ++k) {
                p0 = fmaf(hv[k], whh_g[0][k], p0);
                p1 = fmaf(hv[k], whh_g[1][k], p1);
                p2 = fmaf(hv[k], whh_g[2][k], p2);
                p3 = fmaf(hv[k], whh_g[3][k], p3);
            }
            if (u < 4) {
                float a = d2bias;
                #pragma unroll
                for (int k = 0; k < 16; ++k) a = fmaf(hv[k], d2w[k], a);
                pd2[((size_t)(ts - 1) * 4096 + b) * 4 + u] = a;
            }
        }
        c = fmaf(sigm(p1), c, sigm(p0) * tanh_(p2));
        h = sigm(p3) * tanh_(c);
        h_lds[row][u] = h;
    }
    {
        const float4* hp = (const float4*)&h_lds[row][0];
        #pragma unroll
        for (int qq = 0; qq < 4; ++qq) {
            float4 v = hp[qq];
            hv[4*qq+0] = v.x; hv[4*qq+1] = v.y; hv[4*qq+2] = v.z; hv[4*qq+3] = v.w;
        }
        if (u < 4) {
            float a = d2bias;
            #pragma unroll
            for (int k = 0; k < 16; ++k) a = fmaf(hv[k], d2w[k], a);
            pd2[((size_t)127 * 4096 + b) * 4 + u] = a;
        }
    }
}

// ============ K5: d2 recurrence (H=1), lane = batch ============
__global__ void k5_d2(const float* __restrict__ pd2, const float* __restrict__ d2_Whh,
                      float* __restrict__ d2h)   // [ts][4096]
{
    const int b = blockIdx.x * 256 + threadIdx.x;
    const float w0 = d2_Whh[0], w1 = d2_Whh[1], w2 = d2_Whh[2], w3 = d2_Whh[3];
    const float4* pp = (const float4*)pd2;
    float h = 0.f, c = 0.f;
    for (int ts = 0; ts < 128; ++ts) {
        float4 g4 = pp[(size_t)ts * 4096 + b];
        float gi = fmaf(h, w0, g4.x);
        float gf = fmaf(h, w1, g4.y);
        float gg = fmaf(h, w2, g4.z);
        float go = fmaf(h, w3, g4.w);
        c = fmaf(sigm(gf), c, sigm(gi) * tanh_(gg));
        h = sigm(go) * tanh_(c);
        d2h[(size_t)ts * 4096 + b] = h;
    }
}

// ============ K6: fc1(128->32) + fc2(32->32), 8 batches/block ============
__global__ __launch_bounds__(256) void k6_fc(
    const float* __restrict__ d2h,
    const float* __restrict__ fc1_W, const float* __restrict__ fc1_b,
    const float* __restrict__ fc2_W, const float* __restrict__ fc2_b,
    float* __restrict__ out)
{
    __shared__ float flat_s[8][128];
    __shared__ float mid_s[8][32];
    const int t = threadIdx.x;
    const int s = t >> 5, o = t & 31;
    const size_t b0 = (size_t)blockIdx.x * 8;

    for (int i = t; i < 1024; i += 256) {
        int ts = i >> 3, ss = i & 7;
        flat_s[ss][ts] = d2h[(size_t)ts * 4096 + b0 + ss];
    }
    __syncthreads();

    float a = fc1_b[o];
    {
        const float4* wp = (const float4*)(fc1_W + (size_t)o * 128);
        const float4* fp = (const float4*)flat_s[s];
        #pragma unroll
        for (int qq = 0; qq < 32; ++qq) {
            float4 f = fp[qq], wv = wp[qq];
            a = fmaf(f.x, wv.x, a); a = fmaf(f.y, wv.y, a);
            a = fmaf(f.z, wv.z, a); a = fmaf(f.w, wv.w, a);
        }
    }
    mid_s[s][o] = a;
    __syncthreads();

    float a2 = fc2_b[o];
    {
        const float4* wp = (const float4*)(fc2_W + (size_t)o * 32);
        const float4* mp = (const float4*)mid_s[s];
        #pragma unroll
        for (int qq = 0; qq < 8; ++qq) {
            float4 m = mp[qq], wv = wp[qq];
            a2 = fmaf(m.x, wv.x, a2); a2 = fmaf(m.y, wv.y, a2);
            a2 = fmaf(m.z, wv.z, a2); a2 = fmaf(m.w, wv.w, a2);
        }
    }
    out[(b0 + s) * 32 + o] = a2;
}

extern "C" void kernel_launch(void* const* d_in, const int* in_sizes, int n_in,
                              void* d_out, int out_size, void* d_ws, size_t ws_size,
                              hipStream_t stream) {
    const float* x      = (const float*)d_in[0];
    const float* e1_Wih = (const float*)d_in[1];
    const float* e1_Whh = (const float*)d_in[2];
    const float* e1_b   = (const float*)d_in[3];
    const float* e2_Wih = (const float*)d_in[4];
    const float* e2_Whh = (const float*)d_in[5];
    const float* e2_b   = (const float*)d_in[6];
    const float* d1_Wih = (const float*)d_in[7];
    const float* d1_Whh = (const float*)d_in[8];
    const float* d1_b   = (const float*)d_in[9];
    const float* d2_Wih = (const float*)d_in[10];
    const float* d2_Whh = (const float*)d_in[11];
    const float* d2_b   = (const float*)d_in[12];
    const float* fc1_W  = (const float*)d_in[13];
    const float* fc1_b  = (const float*)d_in[14];
    const float* fc2_W  = (const float*)d_in[15];
    const float* fc2_b  = (const float*)d_in[16];
    float* out = (float*)d_out;

    float* ws     = (float*)d_ws;
    float* pe2    = ws;                 // [96][4096][4]; reused as pd2 [128][4096][4]
    float* dec_in = ws + 2097152;       // [4096][128]
    float* d2h    = ws + 2621440;       // [128][4096]

    hipLaunchKernelGGL(k1_e1, dim3(256), dim3(512), 0, stream,
                       x, e1_Wih, e1_Whh, e1_b, e2_Wih, e2_b, pe2);
    hipLaunchKernelGGL(k2_e2, dim3(16), dim3(256), 0, stream, pe2, e2_Whh, x, dec_in);
    hipLaunchKernelGGL(k3_d1, dim3(256), dim3(256), 0, stream,
                       dec_in, d1_Wih, d1_Whh, d1_b, d2_Wih, d2_b, pe2 /*pd2*/);
    hipLaunchKernelGGL(k5_d2, dim3(16), dim3(256), 0, stream, pe2 /*pd2*/, d2_Whh, d2h);
    hipLaunchKernelGGL(k6_fc, dim3(512), dim3(256), 0, stream,
                       d2h, fc1_W, fc1_b, fc2_W, fc2_b, out);
}

// Round 7
// 175.914 us; speedup vs baseline: 2.7646x; 1.2188x over previous
//
#include <hip/hip_runtime.h>
#include <hip/hip_bf16.h>

typedef __attribute__((ext_vector_type(8))) short bf16x8;
typedef __attribute__((ext_vector_type(4))) float f32x4;

__device__ __forceinline__ float sigm(float x) {
    return __builtin_amdgcn_rcpf(1.0f + __expf(-x));
}
__device__ __forceinline__ float tanh_(float x) {
    float e = __expf(2.0f * x);
    return 1.0f - 2.0f * __builtin_amdgcn_rcpf(e + 1.0f);
}
__device__ __forceinline__ ushort f2bf(float f) {   // RNE float->bf16
    uint u = __float_as_uint(f);
    u = u + 0x7FFFu + ((u >> 16) & 1u);
    return (ushort)(u >> 16);
}
__device__ __forceinline__ float bf2f(ushort s) { return __uint_as_float(((uint)s) << 16); }
__device__ __forceinline__ float sel4(f32x4 a, int k) {   // a[k], divergent k
    float lo = (k & 1) ? a[1] : a[0];
    float hi = (k & 1) ? a[3] : a[2];
    return (k & 2) ? hi : lo;
}
__device__ __forceinline__ float sel4v(float a0, float a1, float a2, float a3, int s) {
    float lo = (s & 1) ? a1 : a0;
    float hi = (s & 1) ? a3 : a2;
    return (s & 2) ? hi : lo;
}

// ============ K1: e1 LSTM(8->64) via MFMA, in-register activations, 1 barrier/step ============
// 16 batches/block, 512 threads (8 waves), grid 256.
// Gate rows reordered unit-major: tile T col q -> (unit = T*4 + (q>>2), gate = q&3),
// weight row = gate*64 + unit. So each 16-col tile holds all 4 gates of 4 units and
// the owning wave does activations straight from the C-fragment (quad transpose via
// 3 divergent-select + shfl_xor), writing h (bf16 hi/lo) to a double-buffered LDS
// array. ONE barrier per step. Tile 16 = e2 xg (unit "64"), on wave 7; its MFMA at
// step ts uses h[ts-1] -> stored to pe2[ts-1] (R5 off-by-one FIXED), pe2[95] done
// post-loop.
__global__ __launch_bounds__(512) __attribute__((amdgpu_waves_per_eu(2, 2)))
void k1_e1(
    const float* __restrict__ x,
    const float* __restrict__ e1_Wih, const float* __restrict__ e1_Whh, const float* __restrict__ e1_b,
    const float* __restrict__ e2_Wih, const float* __restrict__ e2_b,
    float* __restrict__ pe2)   // [ts][4096][4]
{
    __shared__ float x_s[16 * 768];                         // 48 KB
    __shared__ __align__(16) ushort h_hi[2][16 * 72];       // 4.6 KB, rows padded to 72
    __shared__ __align__(16) ushort h_lo[2][16 * 72];       // 4.6 KB
    __shared__ __align__(16) ushort x2_s[2][16 * 40];       // 2.5 KB A2 chunks

    const int t = threadIdx.x;
    const int bBase = blockIdx.x * 16;
    const int l = t & 63, wv = t >> 6;
    const int q = l & 15, sub = l >> 4;
    const int u_loc = q >> 2, g = q & 3;

    // ---- stage x ----
    for (int i = t; i < 16 * 768; i += 512) x_s[i] = x[(size_t)bBase * 768 + i];

    // ---- weight fragments (hi/lo bf16) ----
    auto loadW = [&](const float* rowbase, int k0, bool valid, bf16x8& hi8, bf16x8& lo8) {
        float f[8];
        if (valid) {
            float4 v0 = ((const float4*)(rowbase + k0))[0];
            float4 v1 = ((const float4*)(rowbase + k0))[1];
            f[0]=v0.x; f[1]=v0.y; f[2]=v0.z; f[3]=v0.w;
            f[4]=v1.x; f[5]=v1.y; f[6]=v1.z; f[7]=v1.w;
        } else {
            #pragma unroll
            for (int j = 0; j < 8; ++j) f[j] = 0.f;
        }
        #pragma unroll
        for (int j = 0; j < 8; ++j) {
            ushort h = f2bf(f[j]);
            hi8[j] = (short)h;
            lo8[j] = (short)f2bf(f[j] - bf2f(h));
        }
    };
    auto loadTileB = [&](int T, bf16x8& Bh0, bf16x8& Bh1, bf16x8& Bl0, bf16x8& Bl1, bf16x8& B2) {
        const bool isE2 = (T == 16);
        const bool valid = !isE2 || (u_loc == 0);
        const int wrow = isE2 ? g : (g * 64 + T * 4 + u_loc);
        const float* rowp = isE2 ? (e2_Wih + (size_t)wrow * 64) : (e1_Whh + (size_t)wrow * 64);
        loadW(rowp, sub * 8,      valid, Bh0, Bl0);
        loadW(rowp, 32 + sub * 8, valid, Bh1, Bl1);
        #pragma unroll
        for (int j = 0; j < 8; ++j) B2[j] = 0;
        if (!isE2) {
            if (sub < 3) {       // k 0-7: Wih_hi(*xhi), 8-15: Wih_hi(*xlo), 16-23: Wih_lo(*xhi)
                const float* wr = e1_Wih + (size_t)wrow * 8;
                #pragma unroll
                for (int j = 0; j < 8; ++j) {
                    float f = wr[j];
                    ushort h = f2bf(f);
                    B2[j] = (sub < 2) ? (short)h : (short)f2bf(f - bf2f(h));
                }
            } else {             // k 24,25: bias hi/lo (A2 = 1.0 there)
                float bb = e1_b[wrow];
                ushort h = f2bf(bb);
                B2[0] = (short)h; B2[1] = (short)f2bf(bb - bf2f(h));
            }
        } else if (valid && sub == 3) {
            float bb = e2_b[g];
            ushort h = f2bf(bb);
            B2[0] = (short)h; B2[1] = (short)f2bf(bb - bf2f(h));
        }
    };

    const int T0 = 2 * wv, T1 = 2 * wv + 1;
    bf16x8 B0h0, B0h1, B0l0, B0l1, B0x;
    bf16x8 B1h0, B1h1, B1l0, B1l1, B1x;
    bf16x8 B2h0, B2h1, B2l0, B2l1, B2x;
    loadTileB(T0, B0h0, B0h1, B0l0, B0l1, B0x);
    loadTileB(T1, B1h0, B1h1, B1l0, B1l1, B1x);
    if (wv == 7) loadTileB(16, B2h0, B2h1, B2l0, B2l1, B2x);

    __syncthreads();   // x_s ready

    // ---- init h[0] = 0; x2 buffers (constants in both, x[0] in buf 0) ----
    for (int i = t; i < 16 * 72; i += 512) { h_hi[0][i] = 0; h_lo[0][i] = 0; }
    {
        int bb = t >> 5, pos = t & 31;
        ushort v0 = 0;
        if (pos < 24) {
            float xv = x_s[bb * 768 + (pos & 7)];
            ushort hi = f2bf(xv);
            v0 = (pos < 8) ? hi : (pos < 16) ? f2bf(xv - bf2f(hi)) : hi;
        } else if (pos == 24 || pos == 25) v0 = 0x3F80;
        x2_s[0][bb * 40 + pos] = v0;
        x2_s[1][bb * 40 + pos] = (pos == 24 || pos == 25) ? (ushort)0x3F80 : (ushort)0;
    }

    float c0r = 0.f, c1r = 0.f;    // cell state: (batch 4*sub+g, unit T*4+u_loc) per tile
    __syncthreads();

    #pragma unroll 1
    for (int ts = 0; ts < 96; ++ts) {
        const int p = ts & 1, pn = p ^ 1;

        // ---- A fragments: row = batch q, k = sub*8+j (+32 for c1 chunk) ----
        bf16x8 Ah0 = *(const bf16x8*)&h_hi[p][q * 72 + sub * 8];
        bf16x8 Ah1 = *(const bf16x8*)&h_hi[p][q * 72 + 32 + sub * 8];
        bf16x8 Al0 = *(const bf16x8*)&h_lo[p][q * 72 + sub * 8];
        bf16x8 Al1 = *(const bf16x8*)&h_lo[p][q * 72 + 32 + sub * 8];
        bf16x8 A2v = *(const bf16x8*)&x2_s[p][q * 40 + sub * 8];

        // ---- MFMAs: two parallel chains per tile (3 + 4), then add ----
        f32x4 a0 = {0.f,0.f,0.f,0.f}, e0 = {0.f,0.f,0.f,0.f};
        a0 = __builtin_amdgcn_mfma_f32_16x16x32_bf16(Ah0, B0h0, a0, 0, 0, 0);
        a0 = __builtin_amdgcn_mfma_f32_16x16x32_bf16(Al0, B0h0, a0, 0, 0, 0);
        a0 = __builtin_amdgcn_mfma_f32_16x16x32_bf16(Ah0, B0l0, a0, 0, 0, 0);
        e0 = __builtin_amdgcn_mfma_f32_16x16x32_bf16(Ah1, B0h1, e0, 0, 0, 0);
        e0 = __builtin_amdgcn_mfma_f32_16x16x32_bf16(Al1, B0h1, e0, 0, 0, 0);
        e0 = __builtin_amdgcn_mfma_f32_16x16x32_bf16(Ah1, B0l1, e0, 0, 0, 0);
        e0 = __builtin_amdgcn_mfma_f32_16x16x32_bf16(A2v, B0x,  e0, 0, 0, 0);

        f32x4 a1 = {0.f,0.f,0.f,0.f}, e1 = {0.f,0.f,0.f,0.f};
        a1 = __builtin_amdgcn_mfma_f32_16x16x32_bf16(Ah0, B1h0, a1, 0, 0, 0);
        a1 = __builtin_amdgcn_mfma_f32_16x16x32_bf16(Al0, B1h0, a1, 0, 0, 0);
        a1 = __builtin_amdgcn_mfma_f32_16x16x32_bf16(Ah0, B1l0, a1, 0, 0, 0);
        e1 = __builtin_amdgcn_mfma_f32_16x16x32_bf16(Ah1, B1h1, e1, 0, 0, 0);
        e1 = __builtin_amdgcn_mfma_f32_16x16x32_bf16(Al1, B1h1, e1, 0, 0, 0);
        e1 = __builtin_amdgcn_mfma_f32_16x16x32_bf16(Ah1, B1l1, e1, 0, 0, 0);
        e1 = __builtin_amdgcn_mfma_f32_16x16x32_bf16(A2v, B1x,  e1, 0, 0, 0);

        // ---- e2 tile (wave 7): value = h[ts-1]-based -> pe2[ts-1] ----
        if (wv == 7) {
            f32x4 a2 = {0.f,0.f,0.f,0.f}, e2 = {0.f,0.f,0.f,0.f};
            a2 = __builtin_amdgcn_mfma_f32_16x16x32_bf16(Ah0, B2h0, a2, 0, 0, 0);
            a2 = __builtin_amdgcn_mfma_f32_16x16x32_bf16(Al0, B2h0, a2, 0, 0, 0);
            a2 = __builtin_amdgcn_mfma_f32_16x16x32_bf16(Ah0, B2l0, a2, 0, 0, 0);
            e2 = __builtin_amdgcn_mfma_f32_16x16x32_bf16(Ah1, B2h1, e2, 0, 0, 0);
            e2 = __builtin_amdgcn_mfma_f32_16x16x32_bf16(Al1, B2h1, e2, 0, 0, 0);
            e2 = __builtin_amdgcn_mfma_f32_16x16x32_bf16(Ah1, B2l1, e2, 0, 0, 0);
            e2 = __builtin_amdgcn_mfma_f32_16x16x32_bf16(A2v, B2x,  e2, 0, 0, 0);
            if (ts > 0 && u_loc == 0) {
                f32x4 acc2 = a2 + e2;
                #pragma unroll
                for (int i = 0; i < 4; ++i)
                    pe2[((size_t)(ts - 1) * 4096 + bBase + 4 * sub + i) * 4 + g] = acc2[i];
            }
        }

        // ---- in-register activations per tile: quad transpose then LSTM cell ----
        {
            f32x4 acc = a0 + e0;
            float own = sel4(acc, g);
            float r1 = __shfl_xor(sel4(acc, g ^ 1), 1);
            float r2 = __shfl_xor(sel4(acc, g ^ 2), 2);
            float r3 = __shfl_xor(sel4(acc, g ^ 3), 3);
            float pi = sel4v(own, r1, r2, r3, g);
            float pf = sel4v(own, r1, r2, r3, g ^ 1);
            float pg = sel4v(own, r1, r2, r3, g ^ 2);
            float po = sel4v(own, r1, r2, r3, g ^ 3);
            c0r = fmaf(sigm(pf), c0r, sigm(pi) * tanh_(pg));
            float hv = sigm(po) * tanh_(c0r);
            int idx = (4 * sub + g) * 72 + T0 * 4 + u_loc;
            ushort hh = f2bf(hv);
            h_hi[pn][idx] = hh;
            h_lo[pn][idx] = f2bf(hv - bf2f(hh));
        }
        {
            f32x4 acc = a1 + e1;
            float own = sel4(acc, g);
            float r1 = __shfl_xor(sel4(acc, g ^ 1), 1);
            float r2 = __shfl_xor(sel4(acc, g ^ 2), 2);
            float r3 = __shfl_xor(sel4(acc, g ^ 3), 3);
            float pi = sel4v(own, r1, r2, r3, g);
            float pf = sel4v(own, r1, r2, r3, g ^ 1);
            float pg = sel4v(own, r1, r2, r3, g ^ 2);
            float po = sel4v(own, r1, r2, r3, g ^ 3);
            c1r = fmaf(sigm(pf), c1r, sigm(pi) * tanh_(pg));
            float hv = sigm(po) * tanh_(c1r);
            int idx = (4 * sub + g) * 72 + T1 * 4 + u_loc;
            ushort hh = f2bf(hv);
            h_hi[pn][idx] = hh;
            h_lo[pn][idx] = f2bf(hv - bf2f(hh));
        }

        // ---- build x2[pn] for ts+1 ----
        if (ts < 95) {
            int bb = t >> 5, pos = t & 31;
            if (pos < 24) {
                float xv = x_s[bb * 768 + (ts + 1) * 8 + (pos & 7)];
                ushort hi = f2bf(xv);
                x2_s[pn][bb * 40 + pos] = (pos < 8) ? hi : (pos < 16) ? f2bf(xv - bf2f(hi)) : hi;
            }
        }
        __syncthreads();
    }

    // ---- pe2[95] from final h (in h buffers parity 0) ----
    if (wv == 7) {
        bf16x8 Ah0 = *(const bf16x8*)&h_hi[0][q * 72 + sub * 8];
        bf16x8 Ah1 = *(const bf16x8*)&h_hi[0][q * 72 + 32 + sub * 8];
        bf16x8 Al0 = *(const bf16x8*)&h_lo[0][q * 72 + sub * 8];
        bf16x8 Al1 = *(const bf16x8*)&h_lo[0][q * 72 + 32 + sub * 8];
        bf16x8 A2v = *(const bf16x8*)&x2_s[0][q * 40 + sub * 8];   // only k=24,25 matter
        f32x4 a2 = {0.f,0.f,0.f,0.f}, e2 = {0.f,0.f,0.f,0.f};
        a2 = __builtin_amdgcn_mfma_f32_16x16x32_bf16(Ah0, B2h0, a2, 0, 0, 0);
        a2 = __builtin_amdgcn_mfma_f32_16x16x32_bf16(Al0, B2h0, a2, 0, 0, 0);
        a2 = __builtin_amdgcn_mfma_f32_16x16x32_bf16(Ah0, B2l0, a2, 0, 0, 0);
        e2 = __builtin_amdgcn_mfma_f32_16x16x32_bf16(Ah1, B2h1, e2, 0, 0, 0);
        e2 = __builtin_amdgcn_mfma_f32_16x16x32_bf16(Al1, B2h1, e2, 0, 0, 0);
        e2 = __builtin_amdgcn_mfma_f32_16x16x32_bf16(Ah1, B2l1, e2, 0, 0, 0);
        e2 = __builtin_amdgcn_mfma_f32_16x16x32_bf16(A2v, B2x,  e2, 0, 0, 0);
        if (u_loc == 0) {
            f32x4 acc2 = a2 + e2;
            #pragma unroll
            for (int i = 0; i < 4; ++i)
                pe2[((size_t)95 * 4096 + bBase + 4 * sub + i) * 4 + g] = acc2[i];
        }
    }
}

// ============ K2: e2 recurrence (H=1), lane = batch, depth-16 load pipeline ============
__global__ __launch_bounds__(64) __attribute__((amdgpu_waves_per_eu(2, 2)))
void k2_e2(const float* __restrict__ pe2, const float* __restrict__ e2_Whh,
           const float* __restrict__ x, float* __restrict__ dec_in)   // dec_in [ts][4096]
{
    const int b = blockIdx.x * 64 + threadIdx.x;
    const float w0 = e2_Whh[0], w1 = e2_Whh[1], w2 = e2_Whh[2], w3 = e2_Whh[3];
    const float4* pp = (const float4*)pe2;
    float4 buf[16];
    #pragma unroll
    for (int j = 0; j < 16; ++j) buf[j] = pp[(size_t)j * 4096 + b];
    float h = 0.f, c = 0.f;
    #pragma unroll   // full unroll -> static buf indices, loads 16 steps ahead
    for (int ts = 0; ts < 96; ++ts) {
        float4 g4 = buf[ts & 15];
        if (ts + 16 < 96) buf[ts & 15] = pp[(size_t)(ts + 16) * 4096 + b];
        float gi = fmaf(h, w0, g4.x);
        float gf = fmaf(h, w1, g4.y);
        float gg = fmaf(h, w2, g4.z);
        float go = fmaf(h, w3, g4.w);
        c = fmaf(sigm(gf), c, sigm(gi) * tanh_(gg));
        h = sigm(go) * tanh_(c);
        dec_in[(size_t)ts * 4096 + b] = fmaxf(h, 0.f);
    }
    #pragma unroll 8
    for (int j = 0; j < 32; ++j)
        dec_in[(size_t)(96 + j) * 4096 + b] = x[(size_t)b * 768 + (64 + j) * 8];
}

// ============ K3: decoder fused: d1 LSTM(1->16) + d2(H=1) + fc1 + fc2 ============
// 16 batches/block, 256 threads. d1 as before (4 batches/wave, LDS h round-trip),
// d2 preacts -> LDS (padded stride 516), d2 recurrence by 16 lanes, fc from LDS.
__global__ __launch_bounds__(256, 2) void k3_dec(
    const float* __restrict__ dec_in,
    const float* __restrict__ d1_Wih, const float* __restrict__ d1_Whh, const float* __restrict__ d1_b,
    const float* __restrict__ d2_Wih, const float* __restrict__ d2_b,
    const float* __restrict__ d2_Whh,
    const float* __restrict__ fc1_W, const float* __restrict__ fc1_b,
    const float* __restrict__ fc2_W, const float* __restrict__ fc2_b,
    float* __restrict__ out)
{
    __shared__ float din_s[16 * 129];      // [row][ts], stride 129
    __shared__ float h_lds[16][16];
    __shared__ float pd2_s[16 * 516];      // [row][ts*4+g], stride 516 (16B-aligned rows)
    __shared__ float d2h_s[16 * 132];      // [row][ts], stride 132 (16B-aligned)
    __shared__ float mid_s[16 * 36];       // [row][o], stride 36 (16B-aligned)

    const int t = threadIdx.x;
    const int w = t >> 6, lane = t & 63;
    const int qq4 = lane >> 4, u = lane & 15;
    const int row = w * 4 + qq4;
    const size_t bBase = (size_t)blockIdx.x * 16;

    // stage dec_in (transpose [ts][4096] -> [row][ts])
    for (int i = t; i < 2048; i += 256) {
        int ts = i >> 4, rr = i & 15;
        din_s[rr * 129 + ts] = dec_in[(size_t)ts * 4096 + bBase + rr];
    }

    float wih_g[4], bg[4], whh_g[4][16], d2w[16];
    #pragma unroll
    for (int g = 0; g < 4; ++g) {
        wih_g[g] = d1_Wih[g * 16 + u];
        bg[g]    = d1_b[g * 16 + u];
        const float4* wp = (const float4*)(d1_Whh + (size_t)(g * 16 + u) * 16);
        #pragma unroll
        for (int k4 = 0; k4 < 4; ++k4) {
            float4 v = wp[k4];
            whh_g[g][4*k4+0] = v.x; whh_g[g][4*k4+1] = v.y;
            whh_g[g][4*k4+2] = v.z; whh_g[g][4*k4+3] = v.w;
        }
    }
    {
        const float4* wp = (const float4*)(d2_Wih + (size_t)(u & 3) * 16);
        #pragma unroll
        for (int k4 = 0; k4 < 4; ++k4) {
            float4 v = wp[k4];
            d2w[4*k4+0] = v.x; d2w[4*k4+1] = v.y; d2w[4*k4+2] = v.z; d2w[4*k4+3] = v.w;
        }
    }
    const float d2bias = d2_b[u & 3];

    float h = 0.f, c = 0.f;
    __syncthreads();

    float hv[16];
    for (int ts = 0; ts < 128; ++ts) {
        float xv = din_s[row * 129 + ts];
        float p0 = fmaf(xv, wih_g[0], bg[0]);
        float p1 = fmaf(xv, wih_g[1], bg[1]);
        float p2 = fmaf(xv, wih_g[2], bg[2]);
        float p3 = fmaf(xv, wih_g[3], bg[3]);
        if (ts > 0) {
            const float4* hp = (const float4*)&h_lds[row][0];
            #pragma unroll
            for (int k4 = 0; k4 < 4; ++k4) {
                float4 v = hp[k4];
                hv[4*k4+0] = v.x; hv[4*k4+1] = v.y; hv[4*k4+2] = v.z; hv[4*k4+3] = v.w;
            }
            #pragma unroll
            for (int k = 0; k < 16; ++k) {
                p0 = fmaf(hv[k], whh_g[0][k], p0);
                p1 = fmaf(hv[k], whh_g[1][k], p1);
                p2 = fmaf(hv[k], whh_g[2][k], p2);
                p3 = fmaf(hv[k], whh_g[3][k], p3);
            }
            if (u < 4) {
                float a = d2bias;
                #pragma unroll
                for (int k = 0; k < 16; ++k) a = fmaf(hv[k], d2w[k], a);
                pd2_s[row * 516 + (ts - 1) * 4 + u] = a;
            }
        }
        c = fmaf(sigm(p1), c, sigm(p0) * tanh_(p2));
        h = sigm(p3) * tanh_(c);
        h_lds[row][u] = h;
    }
    {   // final d2 preact (ts = 127)
        const float4* hp = (const float4*)&h_lds[row][0];
        #pragma unroll
        for (int k4 = 0; k4 < 4; ++k4) {
            float4 v = hp[k4];
            hv[4*k4+0] = v.x; hv[4*k4+1] = v.y; hv[4*k4+2] = v.z; hv[4*k4+3] = v.w;
        }
        if (u < 4) {
            float a = d2bias;
            #pragma unroll
            for (int k = 0; k < 16; ++k) a = fmaf(hv[k], d2w[k], a);
            pd2_s[row * 516 + 127 * 4 + u] = a;
        }
    }
    __syncthreads();

    // ---- d2 recurrence: 16 lanes, one batch each ----
    {
        const float w0 = d2_Whh[0], w1 = d2_Whh[1], w2 = d2_Whh[2], w3 = d2_Whh[3];
        if (t < 16) {
            float h2 = 0.f, c2 = 0.f;
            #pragma unroll 8
            for (int ts = 0; ts < 128; ++ts) {
                float4 g4 = *(const float4*)&pd2_s[t * 516 + ts * 4];
                float gi = fmaf(h2, w0, g4.x);
                float gf = fmaf(h2, w1, g4.y);
                float gg = fmaf(h2, w2, g4.z);
                float go = fmaf(h2, w3, g4.w);
                c2 = fmaf(sigm(gf), c2, sigm(gi) * tanh_(gg));
                h2 = sigm(go) * tanh_(c2);
                d2h_s[t * 132 + ts] = h2;
            }
        }
    }
    __syncthreads();

    // ---- fc1 (128->32) + fc2 (32->32); thread -> (batch t>>4, outs o, o+16) ----
    {
        const int bb = t >> 4, o = t & 15;
        float acc0 = fc1_b[o], acc1 = fc1_b[o + 16];
        const float4* wa = (const float4*)(fc1_W + (size_t)o * 128);
        const float4* wb = (const float4*)(fc1_W + (size_t)(o + 16) * 128);
        const float4* fp = (const float4*)&d2h_s[bb * 132];
        #pragma unroll
        for (int k4 = 0; k4 < 32; ++k4) {
            float4 f = fp[k4], va = wa[k4], vb = wb[k4];
            acc0 = fmaf(f.x, va.x, acc0); acc0 = fmaf(f.y, va.y, acc0);
            acc0 = fmaf(f.z, va.z, acc0); acc0 = fmaf(f.w, va.w, acc0);
            acc1 = fmaf(f.x, vb.x, acc1); acc1 = fmaf(f.y, vb.y, acc1);
            acc1 = fmaf(f.z, vb.z, acc1); acc1 = fmaf(f.w, vb.w, acc1);
        }
        mid_s[bb * 36 + o] = acc0;
        mid_s[bb * 36 + o + 16] = acc1;
        __syncthreads();
        float o0 = fc2_b[o], o1 = fc2_b[o + 16];
        const float4* va2 = (const float4*)(fc2_W + (size_t)o * 32);
        const float4* vb2 = (const float4*)(fc2_W + (size_t)(o + 16) * 32);
        const float4* mp = (const float4*)&mid_s[bb * 36];
        #pragma unroll
        for (int k4 = 0; k4 < 8; ++k4) {
            float4 m = mp[k4], va = va2[k4], vb = vb2[k4];
            o0 = fmaf(m.x, va.x, o0); o0 = fmaf(m.y, va.y, o0);
            o0 = fmaf(m.z, va.z, o0); o0 = fmaf(m.w, va.w, o0);
            o1 = fmaf(m.x, vb.x, o1); o1 = fmaf(m.y, vb.y, o1);
            o1 = fmaf(m.z, vb.z, o1); o1 = fmaf(m.w, vb.w, o1);
        }
        out[(bBase + bb) * 32 + o] = o0;
        out[(bBase + bb) * 32 + o + 16] = o1;
    }
}

extern "C" void kernel_launch(void* const* d_in, const int* in_sizes, int n_in,
                              void* d_out, int out_size, void* d_ws, size_t ws_size,
                              hipStream_t stream) {
    const float* x      = (const float*)d_in[0];
    const float* e1_Wih = (const float*)d_in[1];
    const float* e1_Whh = (const float*)d_in[2];
    const float* e1_b   = (const float*)d_in[3];
    const float* e2_Wih = (const float*)d_in[4];
    const float* e2_Whh = (const float*)d_in[5];
    const float* e2_b   = (const float*)d_in[6];
    const float* d1_Wih = (const float*)d_in[7];
    const float* d1_Whh = (const float*)d_in[8];
    const float* d1_b   = (const float*)d_in[9];
    const float* d2_Wih = (const float*)d_in[10];
    const float* d2_Whh = (const float*)d_in[11];
    const float* d2_b   = (const float*)d_in[12];
    const float* fc1_W  = (const float*)d_in[13];
    const float* fc1_b  = (const float*)d_in[14];
    const float* fc2_W  = (const float*)d_in[15];
    const float* fc2_b  = (const float*)d_in[16];
    float* out = (float*)d_out;

    float* ws     = (float*)d_ws;
    float* pe2    = ws;                 // [96][4096][4]
    float* dec_in = ws + 1572864;       // [128][4096]

    hipLaunchKernelGGL(k1_e1, dim3(256), dim3(512), 0, stream,
                       x, e1_Wih, e1_Whh, e1_b, e2_Wih, e2_b, pe2);
    hipLaunchKernelGGL(k2_e2, dim3(64), dim3(64), 0, stream, pe2, e2_Whh, x, dec_in);
    hipLaunchKernelGGL(k3_dec, dim3(256), dim3(256), 0, stream,
                       dec_in, d1_Wih, d1_Whh, d1_b, d2_Wih, d2_b, d2_Whh,
                       fc1_W, fc1_b, fc2_W, fc2_b, out);
}